// Round 5
// baseline (394.374 us; speedup 1.0000x reference)
//
#include <hip/hip_runtime.h>
#include <math.h>

// Problem constants
#define B_   8
#define C_   128
#define C2_  256
#define H_   128
#define W_   128
#define HW_  16384
#define CR_  32
#define EPS_ 1e-5f
#define NS_  32     // n-splits for sim partial sums

typedef _Float16 f16;
typedef f16 f16x8 __attribute__((ext_vector_type(8)));
typedef f16 f16x4 __attribute__((ext_vector_type(4)));
typedef float f32x4 __attribute__((ext_vector_type(4)));

// ---------------------------------------------------------------------------
// Kernel 1: prep — fused (avgpool partial sums) + (NHWC fp16 repack, UNscaled)
// ---------------------------------------------------------------------------
__global__ __launch_bounds__(256) void prep_kernel(
    const float* __restrict__ x1, const float* __restrict__ x2,
    float* __restrict__ avg_sums, f16* __restrict__ xs)
{
    __shared__ f16 T[W_ * 136];
    __shared__ float part[C2_];
    int h = blockIdx.x, b = blockIdx.y;
    int tid = threadIdx.x;
    part[tid] = 0.f;
    f16* out = xs + ((size_t)b * H_ + h) * W_ * C2_;
    for (int p = 0; p < 2; ++p) {
        const float* src = p ? x2 : x1;
        __syncthreads();
        for (int idx = tid; idx < C_ * 32; idx += 256) {
            int c = idx >> 5, w4 = (idx & 31) << 2;
            const float4 v = *(const float4*)&src[(((size_t)b * C_ + c) * H_ + h) * W_ + w4];
            float s = v.x + v.y + v.z + v.w;
            s += __shfl_xor(s, 1, 64);  s += __shfl_xor(s, 2, 64);
            s += __shfl_xor(s, 4, 64);  s += __shfl_xor(s, 8, 64);
            s += __shfl_xor(s, 16, 64);
            if ((tid & 31) == 0) part[p * C_ + c] = s;
            int cs = c ^ (8 * ((idx & 31) & 15));
            T[(w4 + 0) * 136 + cs] = (f16)v.x;
            T[(w4 + 1) * 136 + cs] = (f16)v.y;
            T[(w4 + 2) * 136 + cs] = (f16)v.z;
            T[(w4 + 3) * 136 + cs] = (f16)v.w;
        }
        __syncthreads();
        for (int u = tid; u < W_ * 16; u += 256) {
            int w = u >> 4, o = u & 15;
            f16x8 v = *(const f16x8*)&T[w * 136 + ((o * 8) ^ (8 * ((w >> 2) & 15)))];
            *(f16x8*)&out[w * C2_ + p * C_ + o * 8] = v;
        }
    }
    __syncthreads();
    atomicAdd(&avg_sums[b * C2_ + tid], part[tid]);
}

// ---------------------------------------------------------------------------
// Kernel 2: SE MLP
// ---------------------------------------------------------------------------
__global__ __launch_bounds__(256) void se_mlp_kernel(
    const float* __restrict__ avg_sums, const float* __restrict__ w1,
    const float* __restrict__ w2, float* __restrict__ se)
{
    __shared__ float s_avg[B_ * C2_];
    __shared__ float s_h[B_ * CR_];
    for (int i = threadIdx.x; i < B_ * C2_; i += 256)
        s_avg[i] = avg_sums[i] * (1.f / (float)HW_);
    __syncthreads();
    {
        int i = threadIdx.x;
        int b = i / CR_, j = i % CR_;
        float s = 0.f;
        for (int k = 0; k < C2_; ++k) s += s_avg[b * C2_ + k] * w1[j * C2_ + k];
        s_h[i] = fmaxf(s, 0.f);
    }
    __syncthreads();
    for (int i = threadIdx.x; i < B_ * C2_; i += 256) {
        int b = i / C2_, c = i % C2_;
        float s = 0.f;
        #pragma unroll
        for (int j = 0; j < CR_; ++j) s += s_h[b * CR_ + j] * w2[c * CR_ + j];
        se[i] = 1.f / (1.f + expf(-s));
    }
}

// ---------------------------------------------------------------------------
// Kernel 3: weight repack  conv_w[co][2C][3][3] fp32 -> wt[8cc][9t][128co][32ci]
// (chunk-major so one chunk's 73.7 KB slice is contiguous for LDS staging)
// ---------------------------------------------------------------------------
__global__ __launch_bounds__(256) void wt_build_kernel(
    const float* __restrict__ conv_w, f16* __restrict__ wt)
{
    int idx = blockIdx.x * 256 + threadIdx.x;   // < 294912 exact
    int ci = idx & 31;
    int co = (idx >> 5) & 127;
    int tt = idx >> 12;            // cc*9 + t
    int cc = tt / 9, t = tt - cc * 9;
    wt[idx] = (f16)conv_w[((size_t)co * C2_ + cc * 32 + ci) * 9 + t];
}

// ---------------------------------------------------------------------------
// Kernel 4: conv implicit GEMM, fp16 MFMA, weights staged in LDS per chunk.
// 512 threads (8 waves), 4 output rows, grid 256 = 1 block/CU.
// Wave (orow = w>>1, nh = w&1): M=128 co x N=64 n x 1 row.
// LDS: Ws[9][128][40] (pad-40 -> 2-way-free af reads) 92160 B
//      Xs[(r*4+q)*130+col]*8 (row stride 520B = 8 banks -> kg conflict-free) 49920 B
//      seh 512 B. Total 142592 B dynamic.
// ---------------------------------------------------------------------------
#define WS_F16  46080            // 9*128*40
#define XS_F16  24960            // 24*130*8
#define SMEM_BYTES 142592

__global__ __launch_bounds__(512, 2) void conv_mfma_big(
    const f16* __restrict__ xs, const f16* __restrict__ wt,
    const float* __restrict__ se,
    const float* __restrict__ bn_gamma, const float* __restrict__ bn_beta,
    const float* __restrict__ bn_mean, const float* __restrict__ bn_var,
    f16* __restrict__ yh, f16* __restrict__ yt)
{
    extern __shared__ __align__(16) f16 smem[];
    f16* Ws  = smem;                       // 46080 f16
    f16* Xs  = smem + WS_F16;              // 24960 f16
    f16* seh = smem + WS_F16 + XS_F16;     // 256 f16

    int h0 = blockIdx.x * 4, b = blockIdx.y;
    int tid = threadIdx.x;
    int wave = tid >> 6, lane = tid & 63;
    int orow = wave >> 1, nh = wave & 1;
    int lr = lane & 15, kg = lane >> 4;
    const f16* xsb = xs + (size_t)b * ((size_t)H_ * W_ * C2_);
    const f16* wtb = wt;

    if (tid < 256) seh[tid] = (f16)se[b * C2_ + tid];

    f32x4 acc[8][4];
    #pragma unroll
    for (int i = 0; i < 8; ++i)
        #pragma unroll
        for (int j = 0; j < 4; ++j)
            #pragma unroll
            for (int r = 0; r < 4; ++r) acc[i][j][r] = 0.f;

    for (int cc = 0; cc < 8; ++cc) {
        __syncthreads();
        // stage W chunk: 9 taps x 128 co x 32 ci -> Ws[t][co][40-pad]
        {
            const f16* wsrc = wtb + (size_t)cc * (9 * 128 * 32);
            for (int u = tid; u < 4608; u += 512) {
                int kgu = u & 3, co = (u >> 2) & 127, t = u >> 9;
                f16x8 w = *(const f16x8*)&wsrc[(t * 128 + co) * 32 + kgu * 8];
                *(f16x8*)&Ws[(t * 128 + co) * 40 + kgu * 8] = w;
            }
        }
        // stage X: 6 rows (h0-1..h0+4) x 130 cols x 32 ci, SE-scaled
        for (int u = tid; u < 3120; u += 512) {
            int r = u / 520;
            int rem = u - r * 520;
            int col = rem >> 2, q = rem & 3;
            int gh = h0 - 1 + r, gw = col - 1;
            f16x8 v;
            #pragma unroll
            for (int z = 0; z < 8; ++z) v[z] = (f16)0.f;
            if ((unsigned)gh < (unsigned)H_ && (unsigned)gw < (unsigned)W_) {
                v = *(const f16x8*)&xsb[((size_t)(gh * W_ + gw)) * C2_ + cc * 32 + q * 8];
                f16x8 sv = *(const f16x8*)&seh[cc * 32 + q * 8];
                v = v * sv;
            }
            *(f16x8*)&Xs[((r * 4 + q) * 130 + col) * 8] = v;
        }
        __syncthreads();
        #pragma unroll
        for (int t = 0; t < 9; ++t) {
            const int dh = t / 3, dw = t % 3;
            const int rr = orow + dh;
            f16x8 af[8], bf[4];
            #pragma unroll
            for (int i = 0; i < 8; ++i)
                af[i] = *(const f16x8*)&Ws[(t * 128 + i * 16 + lr) * 40 + kg * 8];
            #pragma unroll
            for (int j = 0; j < 4; ++j)
                bf[j] = *(const f16x8*)&Xs[((rr * 4 + kg) * 130 +
                            (nh * 64 + j * 16 + lr + dw)) * 8];
            #pragma unroll
            for (int i = 0; i < 8; ++i)
                #pragma unroll
                for (int j = 0; j < 4; ++j)
                    acc[i][j] = __builtin_amdgcn_mfma_f32_16x16x32_f16(
                        af[i], bf[j], acc[i][j], 0, 0, 0);
        }
    }
    // epilogue: BN+ReLU; D layout col(lane&15)=n, row=kg*4+r(+16i)=c.
    int h = h0 + orow;
    #pragma unroll
    for (int i = 0; i < 8; ++i) {
        int cb = i * 16 + kg * 4;
        float inv[4], add[4];
        #pragma unroll
        for (int r = 0; r < 4; ++r) {
            int c = cb + r;
            inv[r] = bn_gamma[c] * rsqrtf(bn_var[c] + EPS_);
            add[r] = bn_beta[c] - bn_mean[c] * inv[r];
        }
        #pragma unroll
        for (int j = 0; j < 4; ++j) {
            int n = nh * 64 + j * 16 + lr;
            f16x4 tv;
            #pragma unroll
            for (int r = 0; r < 4; ++r) {
                float v = fmaxf(acc[i][j][r] * inv[r] + add[r], 0.f);
                tv[r] = (f16)v;
                yh[((size_t)b * C_ + cb + r) * HW_ + h * W_ + n] = (f16)v;
            }
            *(f16x4*)&yt[((size_t)b * HW_ + h * W_ + n) * C_ + cb] = tv;
        }
    }
}

// ---------------------------------------------------------------------------
// Kernel 4-FALLBACK: R4 conv (static LDS), wt index updated to chunk-major.
// Used only if hipFuncSetAttribute fails.
// ---------------------------------------------------------------------------
__global__ __launch_bounds__(256, 2) void conv_mfma_kernel(
    const f16* __restrict__ xs, const f16* __restrict__ wt,
    const float* __restrict__ se,
    const float* __restrict__ bn_gamma, const float* __restrict__ bn_beta,
    const float* __restrict__ bn_mean, const float* __restrict__ bn_var,
    f16* __restrict__ yh, f16* __restrict__ yt)
{
    __shared__ f16 Xs[17408];
    __shared__ __align__(16) f16 seh[C2_];
    int h0 = blockIdx.x * 2, b = blockIdx.y;
    int tid = threadIdx.x;
    int wave = tid >> 6, lane = tid & 63;
    int wn = wave;
    int lr = lane & 15, kg = lane >> 4;
    const f16* xsb = xs + (size_t)b * ((size_t)H_ * W_ * C2_);

    seh[tid] = (f16)se[b * C2_ + tid];

    f32x4 acc[2][8][2];
    #pragma unroll
    for (int o = 0; o < 2; ++o)
        #pragma unroll
        for (int i = 0; i < 8; ++i)
            #pragma unroll
            for (int j = 0; j < 2; ++j)
                #pragma unroll
                for (int r = 0; r < 4; ++r) acc[o][i][j][r] = 0.f;

    f16x8 afb[2][8];
    auto ldaf = [&](int cc, int t, f16x8* dst) {
        const f16* wb = wt + ((size_t)(cc * 9 + t) * C_) * 32;
        #pragma unroll
        for (int i = 0; i < 8; ++i)
            dst[i] = *(const f16x8*)&wb[(i * 16 + lr) * 32 + kg * 8];
    };

    for (int cc = 0; cc < 8; ++cc) {
        __syncthreads();
        ldaf(cc, 0, afb[0]);
        for (int u = tid; u < 4 * 130 * 4; u += 256) {
            int r = u / 520;
            int rem = u - r * 520;
            int col = rem >> 2, q = rem & 3;
            int gh = h0 - 1 + r, gw = col - 1;
            f16x8 v;
            #pragma unroll
            for (int z = 0; z < 8; ++z) v[z] = (f16)0.f;
            if ((unsigned)gh < (unsigned)H_ && (unsigned)gw < (unsigned)W_) {
                v = *(const f16x8*)&xsb[((size_t)(gh * W_ + gw)) * C2_ + cc * 32 + q * 8];
                f16x8 sv = *(const f16x8*)&seh[cc * 32 + q * 8];
                v = v * sv;
            }
            *(f16x8*)&Xs[((r * 4 + q) * 132 + col) * 8] = v;
        }
        __syncthreads();
        #pragma unroll
        for (int t = 0; t < 9; ++t) {
            const int dh = t / 3, dw = t % 3;
            if (t < 8) ldaf(cc, t + 1, afb[(t + 1) & 1]);
            const f16x8* af = afb[t & 1];
            #pragma unroll
            for (int o = 0; o < 2; ++o) {
                int r = o + dh;
                f16x8 bf[2];
                #pragma unroll
                for (int j = 0; j < 2; ++j)
                    bf[j] = *(const f16x8*)&Xs[((r * 4 + kg) * 132 +
                                (wn * 32 + j * 16 + lr + dw)) * 8];
                #pragma unroll
                for (int i = 0; i < 8; ++i)
                    #pragma unroll
                    for (int j = 0; j < 2; ++j)
                        acc[o][i][j] = __builtin_amdgcn_mfma_f32_16x16x32_f16(
                            af[i], bf[j], acc[o][i][j], 0, 0, 0);
            }
        }
    }
    #pragma unroll
    for (int o = 0; o < 2; ++o) {
        #pragma unroll
        for (int i = 0; i < 8; ++i) {
            int cb = i * 16 + kg * 4;
            float inv[4], add[4];
            #pragma unroll
            for (int r = 0; r < 4; ++r) {
                int c = cb + r;
                inv[r] = bn_gamma[c] * rsqrtf(bn_var[c] + EPS_);
                add[r] = bn_beta[c] - bn_mean[c] * inv[r];
            }
            #pragma unroll
            for (int j = 0; j < 2; ++j) {
                int n = wn * 32 + j * 16 + lr;
                f16x4 tv;
                #pragma unroll
                for (int r = 0; r < 4; ++r) {
                    float v = fmaxf(acc[o][i][j][r] * inv[r] + add[r], 0.f);
                    tv[r] = (f16)v;
                    yh[((size_t)b * C_ + cb + r) * HW_ + (h0 + o) * W_ + n] = (f16)v;
                }
                *(f16x4*)&yt[((size_t)b * HW_ + (h0 + o) * W_ + n) * C_ + cb] = tv;
            }
        }
    }
}

// ---------------------------------------------------------------------------
// Kernel 5: sim partials via MFMA (unchanged)
// ---------------------------------------------------------------------------
__global__ __launch_bounds__(512) void sim_mfma_kernel(
    const f16* __restrict__ yh, float* __restrict__ simp)
{
    int ns = blockIdx.x, b = blockIdx.y;
    int tid = threadIdx.x, wave = tid >> 6, lane = tid & 63;
    int wm = wave >> 2, wn = wave & 3;
    int lr = lane & 15, kg = lane >> 4;
    const f16* Y = yh + (size_t)b * C_ * HW_;
    int n0 = ns * (HW_ / NS_);

    f32x4 acc[4][2];
    #pragma unroll
    for (int i = 0; i < 4; ++i)
        #pragma unroll
        for (int j = 0; j < 2; ++j)
            #pragma unroll
            for (int r = 0; r < 4; ++r) acc[i][j][r] = 0.f;

    for (int kk = 0; kk < 16; ++kk) {
        int k = n0 + kk * 32 + kg * 8;
        f16x8 af[4], bf[2];
        #pragma unroll
        for (int i = 0; i < 4; ++i)
            af[i] = *(const f16x8*)&Y[(size_t)(wm * 64 + i * 16 + lr) * HW_ + k];
        #pragma unroll
        for (int j = 0; j < 2; ++j)
            bf[j] = *(const f16x8*)&Y[(size_t)(wn * 32 + j * 16 + lr) * HW_ + k];
        #pragma unroll
        for (int i = 0; i < 4; ++i)
            #pragma unroll
            for (int j = 0; j < 2; ++j)
                acc[i][j] = __builtin_amdgcn_mfma_f32_16x16x32_f16(af[i], bf[j], acc[i][j], 0, 0, 0);
    }
    float* dst = simp + (size_t)(ns * B_ + b) * C_ * C_;
    #pragma unroll
    for (int i = 0; i < 4; ++i)
        #pragma unroll
        for (int j = 0; j < 2; ++j)
            #pragma unroll
            for (int r = 0; r < 4; ++r)
                dst[(wm * 64 + i * 16 + kg * 4 + r) * C_ + wn * 32 + j * 16 + lr] = acc[i][j][r];
}

// ---------------------------------------------------------------------------
// Kernel 6: reduce partials + softmax(-sim) -> Ph fp16 (unchanged)
// ---------------------------------------------------------------------------
__global__ __launch_bounds__(128) void softmax_kernel(
    const float* __restrict__ simp, f16* __restrict__ Ph)
{
    int bc = blockIdx.x;
    int b = bc / C_;
    int d = threadIdx.x;
    float s = 0.f;
    for (int ns = 0; ns < NS_; ++ns)
        s += simp[((size_t)(ns * B_ + b) * C_ + (bc % C_)) * C_ + d];
    float v = -s;
    float m = v;
    #pragma unroll
    for (int off = 32; off > 0; off >>= 1) m = fmaxf(m, __shfl_xor(m, off, 64));
    __shared__ float sm[2], ss[2];
    int wid = threadIdx.x >> 6;
    if ((threadIdx.x & 63) == 0) sm[wid] = m;
    __syncthreads();
    m = fmaxf(sm[0], sm[1]);
    float p = expf(v - m);
    float sum = p;
    #pragma unroll
    for (int off = 32; off > 0; off >>= 1) sum += __shfl_xor(sum, off, 64);
    if ((threadIdx.x & 63) == 0) ss[wid] = sum;
    __syncthreads();
    sum = ss[0] + ss[1];
    Ph[(size_t)bc * C_ + d] = (f16)(p / sum);
}

// ---------------------------------------------------------------------------
// Kernel 7: feat = P @ y via MFMA; out = gamma*feat + y (unchanged)
// ---------------------------------------------------------------------------
__global__ __launch_bounds__(256) void feat_mfma_kernel(
    const f16* __restrict__ Ph, const f16* __restrict__ yt,
    const f16* __restrict__ yh,
    const float* __restrict__ gamma, float* __restrict__ out)
{
    int nt = blockIdx.x, b = blockIdx.y;
    int tid = threadIdx.x, wave = tid >> 6, lane = tid & 63;
    int wm = wave >> 1, wn = wave & 1;
    int lr = lane & 15, kg = lane >> 4;
    int n0 = nt * 128;
    const f16* Pb = Ph + (size_t)b * C_ * C_;
    const f16* Yt = yt + (size_t)b * HW_ * C_;

    f32x4 acc[4][4];
    #pragma unroll
    for (int i = 0; i < 4; ++i)
        #pragma unroll
        for (int j = 0; j < 4; ++j)
            #pragma unroll
            for (int r = 0; r < 4; ++r) acc[i][j][r] = 0.f;

    #pragma unroll
    for (int kk = 0; kk < 4; ++kk) {
        int k = kk * 32 + kg * 8;
        f16x8 af[4], bf[4];
        #pragma unroll
        for (int i = 0; i < 4; ++i)
            af[i] = *(const f16x8*)&Pb[(wm * 64 + i * 16 + lr) * C_ + k];
        #pragma unroll
        for (int j = 0; j < 4; ++j)
            bf[j] = *(const f16x8*)&Yt[(size_t)(n0 + wn * 64 + j * 16 + lr) * C_ + k];
        #pragma unroll
        for (int i = 0; i < 4; ++i)
            #pragma unroll
            for (int j = 0; j < 4; ++j)
                acc[i][j] = __builtin_amdgcn_mfma_f32_16x16x32_f16(af[i], bf[j], acc[i][j], 0, 0, 0);
    }
    float g = gamma[0];
    #pragma unroll
    for (int i = 0; i < 4; ++i) {
        int cb = wm * 64 + i * 16 + kg * 4;
        #pragma unroll
        for (int j = 0; j < 4; ++j) {
            int n = n0 + wn * 64 + j * 16 + lr;
            #pragma unroll
            for (int r = 0; r < 4; ++r) {
                float res = (float)yh[((size_t)b * C_ + cb + r) * HW_ + n];
                out[((size_t)b * C_ + cb + r) * HW_ + n] = g * acc[i][j][r] + res;
            }
        }
    }
}

// ---------------------------------------------------------------------------
extern "C" void kernel_launch(void* const* d_in, const int* in_sizes, int n_in,
                              void* d_out, int out_size, void* d_ws, size_t ws_size,
                              hipStream_t stream)
{
    const float* x1       = (const float*)d_in[0];
    const float* x2       = (const float*)d_in[1];
    const float* se_w1    = (const float*)d_in[2];
    const float* se_w2    = (const float*)d_in[3];
    const float* conv_w   = (const float*)d_in[4];
    const float* bn_gamma = (const float*)d_in[5];
    const float* bn_beta  = (const float*)d_in[6];
    const float* bn_mean  = (const float*)d_in[7];
    const float* bn_var   = (const float*)d_in[8];
    const float* gamma    = (const float*)d_in[9];
    float* out = (float*)d_out;

    // Workspace layout — total 135,266,304 B (proven footprint)
    char* ws = (char*)d_ws;
    float* avg  = (float*)(ws);                      //       0 +     8 KB
    float* se   = (float*)(ws + 8192);               //    8192 +     8 KB
    f16*   Ph   = (f16*)  (ws + 16384);              //   16384 +   256 KB
    f16*   wt   = (f16*)  (ws + 278528);             //  278528 +   576 KB
    f16*   xs   = (f16*)  (ws + 1048576);            // 1 MB    +    64 MB
    float* simp = (float*)(ws + 1048576);            // aliases xs (post-conv)
    f16*   yh   = (f16*)  (ws + 68157440);           //         +    32 MB
    f16*   yt   = (f16*)  (ws + 101711872);          //         +    32 MB

    hipMemsetAsync(avg, 0, B_ * C2_ * sizeof(float), stream);
    prep_kernel<<<dim3(H_, B_), 256, 0, stream>>>(x1, x2, avg, xs);
    se_mlp_kernel<<<dim3(1), 256, 0, stream>>>(avg, se_w1, se_w2, se);
    wt_build_kernel<<<dim3(1152), 256, 0, stream>>>(conv_w, wt);

    hipError_t aerr = hipFuncSetAttribute(
        (const void*)conv_mfma_big,
        hipFuncAttributeMaxDynamicSharedMemorySize, SMEM_BYTES);
    if (aerr == hipSuccess) {
        conv_mfma_big<<<dim3(H_ / 4, B_), 512, SMEM_BYTES, stream>>>(
            xs, wt, se, bn_gamma, bn_beta, bn_mean, bn_var, yh, yt);
    } else {
        conv_mfma_kernel<<<dim3(H_ / 2, B_), 256, 0, stream>>>(
            xs, wt, se, bn_gamma, bn_beta, bn_mean, bn_var, yh, yt);
    }

    sim_mfma_kernel<<<dim3(NS_, B_), 512, 0, stream>>>(yh, simp);
    softmax_kernel<<<dim3(B_ * C_), 128, 0, stream>>>(simp, Ph);
    feat_mfma_kernel<<<dim3(HW_ / 128, B_), 256, 0, stream>>>(Ph, yt, yh, gamma, out);
}

// Round 6
// 373.768 us; speedup vs baseline: 1.0551x; 1.0551x over previous
//
#include <hip/hip_runtime.h>
#include <math.h>

// Problem constants
#define B_   8
#define C_   128
#define C2_  256
#define H_   128
#define W_   128
#define HW_  16384
#define CR_  32
#define EPS_ 1e-5f
#define NS_  32     // n-splits for sim partial sums

typedef _Float16 f16;
typedef f16 f16x8 __attribute__((ext_vector_type(8)));
typedef f16 f16x4 __attribute__((ext_vector_type(4)));
typedef float f32x4 __attribute__((ext_vector_type(4)));

// ---------------------------------------------------------------------------
// Kernel 1: prep — avg partials (per-h slices, no atomics) + NHWC f16 repack
//           + fused conv-weight repack (288 elements per block).
// avgp layout [h][b][c] -> fully coalesced writes and reads.
// ---------------------------------------------------------------------------
__global__ __launch_bounds__(256) void prep_kernel(
    const float* __restrict__ x1, const float* __restrict__ x2,
    const float* __restrict__ conv_w,
    float* __restrict__ avgp, f16* __restrict__ xs, f16* __restrict__ wt)
{
    __shared__ f16 T[W_ * 136];
    __shared__ float part[C2_];
    int h = blockIdx.x, b = blockIdx.y;
    int tid = threadIdx.x;
    f16* out = xs + ((size_t)b * H_ + h) * W_ * C2_;
    for (int p = 0; p < 2; ++p) {
        const float* src = p ? x2 : x1;
        __syncthreads();
        for (int idx = tid; idx < C_ * 32; idx += 256) {
            int c = idx >> 5, w4 = (idx & 31) << 2;
            const float4 v = *(const float4*)&src[(((size_t)b * C_ + c) * H_ + h) * W_ + w4];
            float s = v.x + v.y + v.z + v.w;
            s += __shfl_xor(s, 1, 64);  s += __shfl_xor(s, 2, 64);
            s += __shfl_xor(s, 4, 64);  s += __shfl_xor(s, 8, 64);
            s += __shfl_xor(s, 16, 64);
            if ((tid & 31) == 0) part[p * C_ + c] = s;
            int cs = c ^ (8 * ((idx & 31) & 15));
            T[(w4 + 0) * 136 + cs] = (f16)v.x;
            T[(w4 + 1) * 136 + cs] = (f16)v.y;
            T[(w4 + 2) * 136 + cs] = (f16)v.z;
            T[(w4 + 3) * 136 + cs] = (f16)v.w;
        }
        __syncthreads();
        for (int u = tid; u < W_ * 16; u += 256) {
            int w = u >> 4, o = u & 15;
            f16x8 v = *(const f16x8*)&T[w * 136 + ((o * 8) ^ (8 * ((w >> 2) & 15)))];
            *(f16x8*)&out[w * C2_ + p * C_ + o * 8] = v;
        }
    }
    __syncthreads();
    avgp[((size_t)h * B_ + b) * C2_ + tid] = part[tid];
    // fused weight repack: wt[cc][t][co][32ci], 288 elems per block, exact cover
    {
        int base = (b * H_ + h) * 288;
        for (int i = tid; i < 288; i += 256) {
            int idx = base + i;
            int ci = idx & 31;
            int co = (idx >> 5) & 127;
            int tt = idx >> 12;
            int cc = tt / 9, t = tt - cc * 9;
            wt[idx] = (f16)conv_w[((size_t)co * C2_ + cc * 32 + ci) * 9 + t];
        }
    }
}

// ---------------------------------------------------------------------------
// Kernel 2: SE MLP, one block per batch (8 blocks, was 1 -> CU-parallel)
// ---------------------------------------------------------------------------
__global__ __launch_bounds__(256) void se_mlp_kernel(
    const float* __restrict__ avgp, const float* __restrict__ w1,
    const float* __restrict__ w2, float* __restrict__ se)
{
    int b = blockIdx.x;
    __shared__ float s_avg[C2_];
    __shared__ float s_h[CR_];
    float s = 0.f;
    for (int h = 0; h < H_; ++h)
        s += avgp[((size_t)h * B_ + b) * C2_ + threadIdx.x];
    s_avg[threadIdx.x] = s * (1.f / (float)HW_);
    __syncthreads();
    {
        int j = threadIdx.x >> 3, sub = threadIdx.x & 7;   // 8 threads per output
        float a = 0.f;
        #pragma unroll 8
        for (int k = sub * 32; k < sub * 32 + 32; ++k) a += s_avg[k] * w1[j * C2_ + k];
        a += __shfl_xor(a, 1, 64); a += __shfl_xor(a, 2, 64); a += __shfl_xor(a, 4, 64);
        if (sub == 0) s_h[j] = fmaxf(a, 0.f);
    }
    __syncthreads();
    float o = 0.f;
    #pragma unroll
    for (int j = 0; j < CR_; ++j) o += s_h[j] * w2[threadIdx.x * CR_ + j];
    se[b * C2_ + threadIdx.x] = 1.f / (1.f + expf(-o));
}

// ---------------------------------------------------------------------------
// Kernel 3: conv implicit GEMM, fp16 MFMA, LDS-staged W + X with
// register-preload pipelining: chunk cc+1's global loads issue before
// compute(cc), so global latency hides behind MFMA.
// 512 thr (8 waves: orow=w>>1, nh=w&1), 4 output rows, grid 256 = 1 blk/CU.
// Epilogue: BN+ReLU -> yh direct + yt via 4-pass LDS transpose (coalesced).
// ---------------------------------------------------------------------------
#define WS_F16  46080            // 9*128*40
#define XS_F16  24960            // 24*130*8
#define SMEM_BYTES 142592        // (46080+24960+256)*2

__global__ __launch_bounds__(512, 2) void conv_mfma_big(
    const f16* __restrict__ xs, const f16* __restrict__ wt,
    const float* __restrict__ se,
    const float* __restrict__ bn_gamma, const float* __restrict__ bn_beta,
    const float* __restrict__ bn_mean, const float* __restrict__ bn_var,
    f16* __restrict__ yh, f16* __restrict__ yt)
{
    extern __shared__ __align__(16) f16 smem[];
    f16* Ws  = smem;                       // 46080 f16
    f16* Xs  = smem + WS_F16;              // 24960 f16
    f16* seh = smem + WS_F16 + XS_F16;     // 256 f16

    int h0 = blockIdx.x * 4, b = blockIdx.y;
    int tid = threadIdx.x;
    int wave = tid >> 6, lane = tid & 63;
    int orow = wave >> 1, nh = wave & 1;
    int lr = lane & 15, kg = lane >> 4;
    const f16* xsb = xs + (size_t)b * ((size_t)H_ * W_ * C2_);

    if (tid < 256) seh[tid] = (f16)se[b * C2_ + tid];
    __syncthreads();

    f32x4 acc[8][4];
    #pragma unroll
    for (int i = 0; i < 8; ++i)
        #pragma unroll
        for (int j = 0; j < 4; ++j)
            #pragma unroll
            for (int r = 0; r < 4; ++r) acc[i][j][r] = 0.f;

    f16x8 wreg[9], xreg[7];

    auto preload = [&](int cc) {
        const f16* wsrc = wt + (size_t)cc * 36864;
        #pragma unroll
        for (int k = 0; k < 9; ++k)
            wreg[k] = *(const f16x8*)&wsrc[(k * 512 + tid) * 8];
        #pragma unroll
        for (int k = 0; k < 7; ++k) {
            int u = k * 512 + tid;
            f16x8 v;
            #pragma unroll
            for (int z = 0; z < 8; ++z) v[z] = (f16)0.f;
            if (u < 3120) {
                int r = u / 520, rem = u - r * 520;
                int col = rem >> 2, q = rem & 3;
                int gh = h0 - 1 + r, gw = col - 1;
                if ((unsigned)gh < (unsigned)H_ && (unsigned)gw < (unsigned)W_) {
                    v = *(const f16x8*)&xsb[((size_t)(gh * W_ + gw)) * C2_ + cc * 32 + q * 8];
                    f16x8 sv = *(const f16x8*)&seh[cc * 32 + q * 8];
                    v = v * sv;
                }
            }
            xreg[k] = v;
        }
    };

    preload(0);

    for (int cc = 0; cc < 8; ++cc) {
        __syncthreads();            // consumers of previous chunk done
        // regs -> LDS
        #pragma unroll
        for (int k = 0; k < 9; ++k) {
            int u = k * 512 + tid;
            *(f16x8*)&Ws[(u >> 2) * 40 + (u & 3) * 8] = wreg[k];
        }
        #pragma unroll
        for (int k = 0; k < 7; ++k) {
            int u = k * 512 + tid;
            if (u < 3120) {
                int r = u / 520, rem = u - r * 520;
                int col = rem >> 2, q = rem & 3;
                *(f16x8*)&Xs[((r * 4 + q) * 130 + col) * 8] = xreg[k];
            }
        }
        __syncthreads();
        if (cc < 7) preload(cc + 1);   // issues global loads; latency hides behind MFMAs
        #pragma unroll
        for (int t = 0; t < 9; ++t) {
            const int dh = t / 3, dw = t % 3;
            const int rr = orow + dh;
            f16x8 bf[4];
            #pragma unroll
            for (int j = 0; j < 4; ++j)
                bf[j] = *(const f16x8*)&Xs[((rr * 4 + kg) * 130 +
                            (nh * 64 + j * 16 + lr + dw)) * 8];
            #pragma unroll
            for (int half = 0; half < 2; ++half) {
                f16x8 af[4];
                #pragma unroll
                for (int i2 = 0; i2 < 4; ++i2)
                    af[i2] = *(const f16x8*)&Ws[(t * 128 + (half * 4 + i2) * 16 + lr) * 40 + kg * 8];
                #pragma unroll
                for (int i2 = 0; i2 < 4; ++i2)
                    #pragma unroll
                    for (int j = 0; j < 4; ++j)
                        acc[half * 4 + i2][j] = __builtin_amdgcn_mfma_f32_16x16x32_f16(
                            af[i2], bf[j], acc[half * 4 + i2][j], 0, 0, 0);
            }
        }
    }
    // epilogue: BN+ReLU; D layout col(lane&15)=n, row=kg*4+r(+16i)=c.
    int h = h0 + orow;
    f16x4 tvv[8][4];
    #pragma unroll
    for (int i = 0; i < 8; ++i) {
        int cb = i * 16 + kg * 4;
        float inv[4], add[4];
        #pragma unroll
        for (int r = 0; r < 4; ++r) {
            int c = cb + r;
            inv[r] = bn_gamma[c] * rsqrtf(bn_var[c] + EPS_);
            add[r] = bn_beta[c] - bn_mean[c] * inv[r];
        }
        #pragma unroll
        for (int j = 0; j < 4; ++j) {
            int n = nh * 64 + j * 16 + lr;
            f16x4 tv;
            #pragma unroll
            for (int r = 0; r < 4; ++r) {
                float v = fmaxf(acc[i][j][r] * inv[r] + add[r], 0.f);
                tv[r] = (f16)v;
                yh[((size_t)b * C_ + cb + r) * HW_ + h * W_ + n] = (f16)v;
            }
            tvv[i][j] = tv;
        }
    }
    // yt via 4-pass LDS transpose (reuse Xs region: 128*136 f16 = 17408 <= 24960)
    f16* T = Xs;
    for (int ro = 0; ro < 4; ++ro) {
        __syncthreads();
        if (orow == ro) {
            #pragma unroll
            for (int i = 0; i < 8; ++i)
                #pragma unroll
                for (int j = 0; j < 4; ++j)
                    *(f16x4*)&T[(nh * 64 + j * 16 + lr) * 136 + i * 16 + kg * 4] = tvv[i][j];
        }
        __syncthreads();
        for (int u = tid; u < 2048; u += 512) {
            int n = u >> 4, o8 = u & 15;
            *(f16x8*)&yt[((size_t)b * HW_ + (h0 + ro) * W_ + n) * C_ + o8 * 8] =
                *(const f16x8*)&T[n * 136 + o8 * 8];
        }
    }
}

// ---------------------------------------------------------------------------
// Kernel 4: sim partials via MFMA (unchanged)
// ---------------------------------------------------------------------------
__global__ __launch_bounds__(512) void sim_mfma_kernel(
    const f16* __restrict__ yh, float* __restrict__ simp)
{
    int ns = blockIdx.x, b = blockIdx.y;
    int tid = threadIdx.x, wave = tid >> 6, lane = tid & 63;
    int wm = wave >> 2, wn = wave & 3;
    int lr = lane & 15, kg = lane >> 4;
    const f16* Y = yh + (size_t)b * C_ * HW_;
    int n0 = ns * (HW_ / NS_);

    f32x4 acc[4][2];
    #pragma unroll
    for (int i = 0; i < 4; ++i)
        #pragma unroll
        for (int j = 0; j < 2; ++j)
            #pragma unroll
            for (int r = 0; r < 4; ++r) acc[i][j][r] = 0.f;

    for (int kk = 0; kk < 16; ++kk) {
        int k = n0 + kk * 32 + kg * 8;
        f16x8 af[4], bf[2];
        #pragma unroll
        for (int i = 0; i < 4; ++i)
            af[i] = *(const f16x8*)&Y[(size_t)(wm * 64 + i * 16 + lr) * HW_ + k];
        #pragma unroll
        for (int j = 0; j < 2; ++j)
            bf[j] = *(const f16x8*)&Y[(size_t)(wn * 32 + j * 16 + lr) * HW_ + k];
        #pragma unroll
        for (int i = 0; i < 4; ++i)
            #pragma unroll
            for (int j = 0; j < 2; ++j)
                acc[i][j] = __builtin_amdgcn_mfma_f32_16x16x32_f16(af[i], bf[j], acc[i][j], 0, 0, 0);
    }
    float* dst = simp + (size_t)(ns * B_ + b) * C_ * C_;
    #pragma unroll
    for (int i = 0; i < 4; ++i)
        #pragma unroll
        for (int j = 0; j < 2; ++j)
            #pragma unroll
            for (int r = 0; r < 4; ++r)
                dst[(wm * 64 + i * 16 + kg * 4 + r) * C_ + wn * 32 + j * 16 + lr] = acc[i][j][r];
}

// ---------------------------------------------------------------------------
// Kernel 5: reduce partials + softmax(-sim) -> Ph fp16 (unchanged)
// ---------------------------------------------------------------------------
__global__ __launch_bounds__(128) void softmax_kernel(
    const float* __restrict__ simp, f16* __restrict__ Ph)
{
    int bc = blockIdx.x;
    int b = bc / C_;
    int d = threadIdx.x;
    float s = 0.f;
    for (int ns = 0; ns < NS_; ++ns)
        s += simp[((size_t)(ns * B_ + b) * C_ + (bc % C_)) * C_ + d];
    float v = -s;
    float m = v;
    #pragma unroll
    for (int off = 32; off > 0; off >>= 1) m = fmaxf(m, __shfl_xor(m, off, 64));
    __shared__ float sm[2], ss[2];
    int wid = threadIdx.x >> 6;
    if ((threadIdx.x & 63) == 0) sm[wid] = m;
    __syncthreads();
    m = fmaxf(sm[0], sm[1]);
    float p = expf(v - m);
    float sum = p;
    #pragma unroll
    for (int off = 32; off > 0; off >>= 1) sum += __shfl_xor(sum, off, 64);
    if ((threadIdx.x & 63) == 0) ss[wid] = sum;
    __syncthreads();
    sum = ss[0] + ss[1];
    Ph[(size_t)bc * C_ + d] = (f16)(p / sum);
}

// ---------------------------------------------------------------------------
// Kernel 6: feat = P @ y via MFMA; out = gamma*feat + y (unchanged)
// ---------------------------------------------------------------------------
__global__ __launch_bounds__(256) void feat_mfma_kernel(
    const f16* __restrict__ Ph, const f16* __restrict__ yt,
    const f16* __restrict__ yh,
    const float* __restrict__ gamma, float* __restrict__ out)
{
    int nt = blockIdx.x, b = blockIdx.y;
    int tid = threadIdx.x, wave = tid >> 6, lane = tid & 63;
    int wm = wave >> 1, wn = wave & 1;
    int lr = lane & 15, kg = lane >> 4;
    int n0 = nt * 128;
    const f16* Pb = Ph + (size_t)b * C_ * C_;
    const f16* Yt = yt + (size_t)b * HW_ * C_;

    f32x4 acc[4][4];
    #pragma unroll
    for (int i = 0; i < 4; ++i)
        #pragma unroll
        for (int j = 0; j < 4; ++j)
            #pragma unroll
            for (int r = 0; r < 4; ++r) acc[i][j][r] = 0.f;

    #pragma unroll
    for (int kk = 0; kk < 4; ++kk) {
        int k = kk * 32 + kg * 8;
        f16x8 af[4], bf[4];
        #pragma unroll
        for (int i = 0; i < 4; ++i)
            af[i] = *(const f16x8*)&Pb[(wm * 64 + i * 16 + lr) * C_ + k];
        #pragma unroll
        for (int j = 0; j < 4; ++j)
            bf[j] = *(const f16x8*)&Yt[(size_t)(n0 + wn * 64 + j * 16 + lr) * C_ + k];
        #pragma unroll
        for (int i = 0; i < 4; ++i)
            #pragma unroll
            for (int j = 0; j < 4; ++j)
                acc[i][j] = __builtin_amdgcn_mfma_f32_16x16x32_f16(af[i], bf[j], acc[i][j], 0, 0, 0);
    }
    float g = gamma[0];
    #pragma unroll
    for (int i = 0; i < 4; ++i) {
        int cb = wm * 64 + i * 16 + kg * 4;
        #pragma unroll
        for (int j = 0; j < 4; ++j) {
            int n = n0 + wn * 64 + j * 16 + lr;
            #pragma unroll
            for (int r = 0; r < 4; ++r) {
                float res = (float)yh[((size_t)b * C_ + cb + r) * HW_ + n];
                out[((size_t)b * C_ + cb + r) * HW_ + n] = g * acc[i][j][r] + res;
            }
        }
    }
}

// ---------------------------------------------------------------------------
extern "C" void kernel_launch(void* const* d_in, const int* in_sizes, int n_in,
                              void* d_out, int out_size, void* d_ws, size_t ws_size,
                              hipStream_t stream)
{
    const float* x1       = (const float*)d_in[0];
    const float* x2       = (const float*)d_in[1];
    const float* se_w1    = (const float*)d_in[2];
    const float* se_w2    = (const float*)d_in[3];
    const float* conv_w   = (const float*)d_in[4];
    const float* bn_gamma = (const float*)d_in[5];
    const float* bn_beta  = (const float*)d_in[6];
    const float* bn_mean  = (const float*)d_in[7];
    const float* bn_var   = (const float*)d_in[8];
    const float* gamma    = (const float*)d_in[9];
    float* out = (float*)d_out;

    // Workspace layout — total 135,266,304 B (proven footprint)
    char* ws = (char*)d_ws;
    float* se   = (float*)(ws + 8192);               //    8192 +     8 KB
    f16*   Ph   = (f16*)  (ws + 16384);              //   16384 +   256 KB
    f16*   wt   = (f16*)  (ws + 278528);             //  278528 +   576 KB
    f16*   xs   = (f16*)  (ws + 1048576);            // 1 MB    +    64 MB
    float* simp = (float*)(ws + 1048576);            // aliases xs (post-conv)
    f16*   yh   = (f16*)  (ws + 68157440);           //         +    32 MB
    float* avgp = (float*)(ws + 68157440);           // aliases yh (pre-conv), 1 MB
    f16*   yt   = (f16*)  (ws + 101711872);          //         +    32 MB

    prep_kernel<<<dim3(H_, B_), 256, 0, stream>>>(x1, x2, conv_w, avgp, xs, wt);
    se_mlp_kernel<<<dim3(B_), 256, 0, stream>>>(avgp, se_w1, se_w2, se);

    hipFuncSetAttribute((const void*)conv_mfma_big,
        hipFuncAttributeMaxDynamicSharedMemorySize, SMEM_BYTES);
    conv_mfma_big<<<dim3(H_ / 4, B_), 512, SMEM_BYTES, stream>>>(
        xs, wt, se, bn_gamma, bn_beta, bn_mean, bn_var, yh, yt);

    sim_mfma_kernel<<<dim3(NS_, B_), 512, 0, stream>>>(yh, simp);
    softmax_kernel<<<dim3(B_ * C_), 128, 0, stream>>>(simp, Ph);
    feat_mfma_kernel<<<dim3(HW_ / 128, B_), 256, 0, stream>>>(Ph, yt, yh, gamma, out);
}